// Round 1
// baseline (4908.453 us; speedup 1.0000x reference)
//
#include <hip/hip_runtime.h>

#define BATCH 16
#define CIN   64
#define COUT  64
#define NG    8
#define HH    64
#define WW    64
#define HW    (HH*WW)
#define TILE  16
#define CHB   16            // output channels per block
#define KITER (CIN*NG)      // 512 reduction steps

// u[g][s] = COMP[INV[g]][s] for p4m, in closed form.
// g = m*4 + r (m: reflection bit, r: rotation). Verified against the
// reference COMP/INV tables on representative elements.
__device__ __forceinline__ int u_index(int g, int s) {
    int r  = g & 3, m  = g >> 2;
    int r2 = s & 3, ms = s >> 2;
    if (!m) { int rr = (r2 - r) & 3; return ms ? (4 + rr) : rr; }
    else    { int rr = (r - r2) & 3; return ms ? rr : (4 + rr); }
}

__global__ __launch_bounds__(256) void gconv_direct(
    const float* __restrict__ x,
    const float* __restrict__ wrel,
    const float* __restrict__ bias,
    float* __restrict__ out)
{
    __shared__ float xs[18][20];   // 16x16 tile + 1 halo, padded stride
    __shared__ float ws[CHB][9];   // transformed weights for this (ci,s)

    const int st  = blockIdx.x;    // spatial tile 0..15 (4x4 of 16x16)
    const int ct  = blockIdx.y;    // channel tile 0..31
    const int b   = blockIdx.z;    // batch 0..15

    const int h0  = (st >> 2) * TILE;
    const int w0  = (st & 3) * TILE;
    const int oc0 = ct * CHB;

    const int tid = threadIdx.x;
    const int ch  = tid & 15;      // local output channel
    const int blk = tid >> 4;      // 4x4 pixel block id (0..15)
    const int by  = (blk >> 2) * 4;
    const int bx  = (blk & 3) * 4;

    const int oc = oc0 + ch;       // oc = co*8 + g  (output layout [b][co][g])
    const int g  = oc & 7;
    const int co = oc >> 3;

    // Weight-loader role (threads 0..143): precompute the spatial tap map
    // for transform T_g: bank_g[i,j] = W[a0, m ? 2-b0 : b0]
    const int wl_c  = tid / 9;           // local channel being loaded
    const int wl_k  = tid - wl_c * 9;    // tap 0..8
    const int wl_i  = wl_k / 3;
    const int wl_j  = wl_k - wl_i * 3;
    const int wl_oc = oc0 + wl_c;
    const int wl_g  = wl_oc & 7;
    const int wl_co = wl_oc >> 3;
    int a0, b0;
    {
        const int r = wl_g & 3, m = wl_g >> 2;
        switch (r) {
            case 0:  a0 = wl_i;     b0 = wl_j;     break;
            case 1:  a0 = wl_j;     b0 = 2 - wl_i; break;
            case 2:  a0 = 2 - wl_i; b0 = 2 - wl_j; break;
            default: a0 = 2 - wl_j; b0 = wl_i;     break;
        }
        if (m) b0 = 2 - b0;
    }

    float acc[4][4];
    #pragma unroll
    for (int i = 0; i < 4; ++i)
        #pragma unroll
        for (int j = 0; j < 4; ++j) acc[i][j] = 0.f;

    for (int t = 0; t < KITER; ++t) {
        const int ci = t >> 3;
        const int s  = t & 7;

        __syncthreads();   // previous compute done before LDS overwrite

        // --- stage 18x18 x tile (zero-padded at image boundary) ---
        const float* xp = x + (((size_t)(b * CIN + ci) * NG + s) * HW);
        for (int idx = tid; idx < 18 * 18; idx += 256) {
            const int rr = idx / 18;
            const int cc = idx - rr * 18;
            const int gh = h0 - 1 + rr;
            const int gw = w0 - 1 + cc;
            float v = 0.f;
            if (gh >= 0 && gh < HH && gw >= 0 && gw < WW)
                v = xp[gh * WW + gw];
            xs[rr][cc] = v;
        }

        // --- stage 16 channels x 9 transformed weights ---
        if (tid < CHB * 9) {
            const int u = u_index(wl_g, s);
            ws[wl_c][wl_k] =
                wrel[((size_t)(wl_co * CIN + ci) * NG + u) * 9 + a0 * 3 + b0];
        }

        __syncthreads();

        // --- compute: 4x4 pixels x 9 taps, all operands in registers ---
        float wr[9];
        #pragma unroll
        for (int k = 0; k < 9; ++k) wr[k] = ws[ch][k];

        float xv[6][6];
        #pragma unroll
        for (int i = 0; i < 6; ++i)
            #pragma unroll
            for (int j = 0; j < 6; ++j)
                xv[i][j] = xs[by + i][bx + j];

        #pragma unroll
        for (int py = 0; py < 4; ++py)
            #pragma unroll
            for (int px = 0; px < 4; ++px)
                #pragma unroll
                for (int ki = 0; ki < 3; ++ki)
                    #pragma unroll
                    for (int kj = 0; kj < 3; ++kj)
                        acc[py][px] += xv[py + ki][px + kj] * wr[ki * 3 + kj];
    }

    const float bv = bias[co];
    float* op = out + (((size_t)(b * COUT + co) * NG + g) * HW);
    #pragma unroll
    for (int py = 0; py < 4; ++py)
        #pragma unroll
        for (int px = 0; px < 4; ++px)
            op[(h0 + by + py) * WW + (w0 + bx + px)] = acc[py][px] + bv;
}

extern "C" void kernel_launch(void* const* d_in, const int* in_sizes, int n_in,
                              void* d_out, int out_size, void* d_ws, size_t ws_size,
                              hipStream_t stream) {
    const float* x    = (const float*)d_in[0];
    const float* wrel = (const float*)d_in[1];
    const float* bias = (const float*)d_in[2];
    float* out        = (float*)d_out;

    dim3 grid(16, 32, 16);   // (spatial tiles, channel tiles, batch)
    gconv_direct<<<grid, 256, 0, stream>>>(x, wrel, bias, out);
}

// Round 2
// 451.668 us; speedup vs baseline: 10.8674x; 10.8674x over previous
//
#include <hip/hip_runtime.h>
#include <stdint.h>

typedef short  bf16x8 __attribute__((ext_vector_type(8)));
typedef float  f32x4  __attribute__((ext_vector_type(4)));

// ---------------- common helpers ----------------

__device__ __forceinline__ short f2bf(float f) {
    uint32_t u = __builtin_bit_cast(uint32_t, f);
    u += 0x7FFFu + ((u >> 16) & 1u);          // RNE to bf16
    return (short)(u >> 16);
}

// u[g][s] = COMP[INV[g]][s] for p4m (verified by round-1 pass)
__device__ __forceinline__ int u_index(int g, int s) {
    int r  = g & 3, m  = g >> 2;
    int r2 = s & 3, ms = s >> 2;
    if (!m) { int rr = (r2 - r) & 3; return ms ? (4 + rr) : rr; }
    else    { int rr = (r - r2) & 3; return ms ? rr : (4 + rr); }
}

// async global->LDS, 16B per lane. lds ptr must be wave-uniform base;
// HW adds lane*16. global ptr is per-lane.
__device__ __forceinline__ void gload_lds16(const void* g, void* l) {
    __builtin_amdgcn_global_load_lds(
        (const __attribute__((address_space(1))) uint32_t*)g,
        (__attribute__((address_space(3))) uint32_t*)l, 16, 0, 0);
}

// ---------------- workspace layout ----------------
// xb  : bf16 [16][66][66][512]   zero-padded NHWC input
// bank: bf16 [9][16][4][512][8]  transformed weights, fragment-ordered
#define XB_ELEMS  (16LL * 66 * 66 * 512)
#define XB_BYTES  (XB_ELEMS * 2)
#define BK_ELEMS  (9LL * 16 * 4 * 512 * 8)
#define BK_BYTES  (BK_ELEMS * 2)
#define WS_NEEDED (XB_BYTES + BK_BYTES)

// ---------------- prep kernels ----------------

// x[b][k][64][64] fp32 (k = ci*8+s) -> xb[b][h+1][w+1][k] bf16 (interior only;
// border comes from the memset)
__global__ __launch_bounds__(256) void prep_x(const float* __restrict__ x,
                                              short* __restrict__ xb) {
    int tid = blockIdx.x * 256 + threadIdx.x;   // 16*64*64*64 = 4.19M
    int kg8 = (tid & 63) * 8;
    int p   = tid >> 6;
    int w   = p & 63;
    int h   = (p >> 6) & 63;
    int b   = p >> 12;
    const float* xp = x + ((size_t)(b * 512 + kg8) * 4096 + h * 64 + w);
    bf16x8 v;
    #pragma unroll
    for (int j = 0; j < 8; ++j) v[j] = f2bf(xp[(size_t)j * 4096]);
    size_t o = (((size_t)b * 66 + h + 1) * 66 + (w + 1)) * 512 + kg8;
    *reinterpret_cast<bf16x8*>(&xb[o]) = v;
}

// wrel fp32 [64][64][8][3][3] -> bank bf16 [t][kc][kg][oc][8]
__global__ __launch_bounds__(256) void prep_w(const float* __restrict__ wrel,
                                              short* __restrict__ bank) {
    int tg = blockIdx.x * 256 + threadIdx.x;    // 9*16*4*512 = 294912
    int oc = tg & 511;
    int r1 = tg >> 9;
    int kg = r1 & 3;
    int r2 = r1 >> 2;
    int kc = r2 & 15;
    int t  = r2 >> 4;
    int ki = t / 3, kj = t - ki * 3;
    int g = oc & 7, co = oc >> 3;
    int r = g & 3, m = g >> 2;
    int a0, b0;
    switch (r) {
        case 0:  a0 = ki;     b0 = kj;     break;
        case 1:  a0 = kj;     b0 = 2 - ki; break;
        case 2:  a0 = 2 - ki; b0 = 2 - kj; break;
        default: a0 = 2 - kj; b0 = ki;     break;
    }
    if (m) b0 = 2 - b0;
    int ci = kc * 4 + kg;                        // k>>3 with k = kc*32+kg*8+j
    const float* wp = wrel + (size_t)(co * 64 + ci) * 72 + a0 * 3 + b0;
    bf16x8 v;
    #pragma unroll
    for (int j = 0; j < 8; ++j) {
        int u = u_index(g, j);                   // s = j
        v[j] = f2bf(wp[u * 9]);
    }
    *reinterpret_cast<bf16x8*>(&bank[(size_t)tg * 8]) = v;
}

// ---------------- main MFMA kernel ----------------
// block: 64 oc x 256 px (16x16 spatial tile), 4 waves, each wave = 64oc x 64px
// (4 image rows). K-loop: 16 chunks of 32 channels x 9 taps.
__global__ __launch_bounds__(256) void gconv_mfma(const short* __restrict__ xb,
                                                  const short* __restrict__ bank,
                                                  const float* __restrict__ bias,
                                                  float* __restrict__ out) {
    // xs: [kg 4][px 336(pad of 324=18*18)][8k]  -> slot = kg*336+px, 16B each
    // ws: [t 9][kg 4][oc 64][8k]                -> slot = (t*4+kg)*64+oc
    __shared__ __attribute__((aligned(16))) short xs[4 * 336 * 8];   // 21504 B
    __shared__ __attribute__((aligned(16))) short wsm[9 * 4 * 64 * 8]; // 36864 B

    const int st  = blockIdx.x;           // 16 spatial tiles
    const int ot  = blockIdx.y;           // 8 oc tiles
    const int b   = blockIdx.z;           // 16 batches
    const int h0  = (st >> 2) * 16;
    const int w0  = (st & 3) * 16;
    const int oc0 = ot * 64;

    const int tid  = threadIdx.x;
    const int lane = tid & 63;
    const int wid  = tid >> 6;
    const int l15  = lane & 15;
    const int lkg  = lane >> 4;

    f32x4 acc[4][4];
    #pragma unroll
    for (int i = 0; i < 4; ++i)
        #pragma unroll
        for (int j = 0; j < 4; ++j)
            #pragma unroll
            for (int e = 0; e < 4; ++e) acc[i][j][e] = 0.f;

    const int xrow_base = (b * 66 + h0) * 66 + w0;   // padded coords

    for (int kc = 0; kc < 16; ++kc) {
        __syncthreads();

        // ---- stage weights: 36 wave-iters, uniform (t,kg) per iter ----
        #pragma unroll
        for (int q = 0; q < 9; ++q) {
            int it = wid + 4 * q;                    // 0..35
            int t  = it >> 2, kg = it & 3;
            const short* src = bank +
                ((size_t)((t * 16 + kc) * 4 + kg) * 512 + oc0 + lane) * 8;
            gload_lds16(src, &wsm[it * 512]);
        }
        // ---- stage x tile: 21 wave-iters (wave0 gets 6) ----
        for (int it = wid; it < 21; it += 4) {
            int slot = it * 64 + lane;               // 0..1343
            int kg = slot / 336;
            int px = slot - kg * 336;
            px = px < 324 ? px : 323;                // pad slots -> harmless dup
            int r = px / 18;
            int c = px - r * 18;
            const short* src = xb +
                ((size_t)(xrow_base + r * 66 + c) * 512 + kc * 32 + kg * 8);
            gload_lds16(src, &xs[it * 512]);
        }

        __syncthreads();

        // ---- compute: 9 taps x (4 A-frags, 4 B-frags, 16 MFMAs) ----
        #pragma unroll
        for (int t = 0; t < 9; ++t) {
            const int ki = t / 3, kj = t - (t / 3) * 3;
            bf16x8 a[4], bf[4];
            #pragma unroll
            for (int mi = 0; mi < 4; ++mi)
                a[mi] = *reinterpret_cast<const bf16x8*>(
                    &wsm[((t * 4 + lkg) * 64 + mi * 16 + l15) * 8]);
            #pragma unroll
            for (int nj = 0; nj < 4; ++nj)
                bf[nj] = *reinterpret_cast<const bf16x8*>(
                    &xs[(lkg * 336 + (wid * 4 + nj + ki) * 18 + l15 + kj) * 8]);
            #pragma unroll
            for (int mi = 0; mi < 4; ++mi)
                #pragma unroll
                for (int nj = 0; nj < 4; ++nj)
                    acc[mi][nj] = __builtin_amdgcn_mfma_f32_16x16x32_bf16(
                        a[mi], bf[nj], acc[mi][nj], 0, 0, 0);
        }
    }

    // ---- epilogue: D row=(lane>>4)*4+reg -> oc, col=lane&15 -> pixel x ----
    #pragma unroll
    for (int mi = 0; mi < 4; ++mi) {
        #pragma unroll
        for (int j = 0; j < 4; ++j) {
            const int oc_g = oc0 + mi * 16 + lkg * 4 + j;
            const float bv = bias[oc_g >> 3];
            float* op = out + ((size_t)b * 512 + oc_g) * 4096 + w0 + l15;
            #pragma unroll
            for (int nj = 0; nj < 4; ++nj)
                op[(h0 + wid * 4 + nj) * 64] = acc[mi][nj][j] + bv,
                op += 0;   // keep op base; row term varies via index
        }
    }
}

// ---------------- round-1 fp32 fallback (ws too small) ----------------
__global__ __launch_bounds__(256) void gconv_direct(
    const float* __restrict__ x, const float* __restrict__ wrel,
    const float* __restrict__ bias, float* __restrict__ out)
{
    __shared__ float xsf[18][20];
    __shared__ float wsf[16][9];
    const int st = blockIdx.x, ct = blockIdx.y, b = blockIdx.z;
    const int h0 = (st >> 2) * 16, w0 = (st & 3) * 16, oc0 = ct * 16;
    const int tid = threadIdx.x;
    const int ch = tid & 15, blk = tid >> 4;
    const int by = (blk >> 2) * 4, bx = (blk & 3) * 4;
    const int oc = oc0 + ch, g = oc & 7, co = oc >> 3;
    const int wl_c = tid / 9, wl_k = tid - wl_c * 9;
    const int wl_i = wl_k / 3, wl_j = wl_k - wl_i * 3;
    const int wl_oc = oc0 + wl_c, wl_g = wl_oc & 7, wl_co = wl_oc >> 3;
    int a0, b0;
    { const int r = wl_g & 3, m = wl_g >> 2;
      switch (r) { case 0: a0=wl_i; b0=wl_j; break; case 1: a0=wl_j; b0=2-wl_i; break;
                   case 2: a0=2-wl_i; b0=2-wl_j; break; default: a0=2-wl_j; b0=wl_i; break; }
      if (m) b0 = 2 - b0; }
    float acc[4][4];
    #pragma unroll
    for (int i=0;i<4;++i) for (int j=0;j<4;++j) acc[i][j]=0.f;
    for (int t = 0; t < 512; ++t) {
        const int ci = t >> 3, s = t & 7;
        __syncthreads();
        const float* xp = x + (((size_t)(b * 64 + ci) * 8 + s) * 4096);
        for (int idx = tid; idx < 18 * 18; idx += 256) {
            const int rr = idx / 18, cc = idx - rr * 18;
            const int gh = h0 - 1 + rr, gw = w0 - 1 + cc;
            float v = 0.f;
            if (gh >= 0 && gh < 64 && gw >= 0 && gw < 64) v = xp[gh * 64 + gw];
            xsf[rr][cc] = v;
        }
        if (tid < 144) {
            const int u = u_index(wl_g, s);
            wsf[wl_c][wl_k] = wrel[((size_t)(wl_co*64+ci)*8+u)*9 + a0*3 + b0];
        }
        __syncthreads();
        float wr[9];
        #pragma unroll
        for (int k=0;k<9;++k) wr[k]=wsf[ch][k];
        float xv[6][6];
        #pragma unroll
        for (int i=0;i<6;++i) for (int j=0;j<6;++j) xv[i][j]=xsf[by+i][bx+j];
        #pragma unroll
        for (int py=0;py<4;++py) for (int px=0;px<4;++px)
            for (int ki=0;ki<3;++ki) for (int kj=0;kj<3;++kj)
                acc[py][px] += xv[py+ki][px+kj]*wr[ki*3+kj];
    }
    const float bv = bias[co];
    float* op = out + (((size_t)(b*64+co)*8+g)*4096);
    #pragma unroll
    for (int py=0;py<4;++py) for (int px=0;px<4;++px)
        op[(h0+by+py)*64 + (w0+bx+px)] = acc[py][px] + bv;
}

// ---------------- launch ----------------
extern "C" void kernel_launch(void* const* d_in, const int* in_sizes, int n_in,
                              void* d_out, int out_size, void* d_ws, size_t ws_size,
                              hipStream_t stream) {
    const float* x    = (const float*)d_in[0];
    const float* wrel = (const float*)d_in[1];
    const float* bias = (const float*)d_in[2];
    float* out        = (float*)d_out;

    if (ws_size >= (size_t)WS_NEEDED) {
        short* xb   = (short*)d_ws;
        short* bank = (short*)((char*)d_ws + XB_BYTES);
        // zero border of padded NHWC buffer (and everything else in it)
        hipMemsetAsync(d_ws, 0, (size_t)XB_BYTES, stream);
        prep_x<<<16384, 256, 0, stream>>>(x, xb);
        prep_w<<<1152, 256, 0, stream>>>(wrel, bank);
        dim3 grid(16, 8, 16);
        gconv_mfma<<<grid, 256, 0, stream>>>(xb, bank, bias, out);
    } else {
        dim3 grid(16, 32, 16);
        gconv_direct<<<grid, 256, 0, stream>>>(x, wrel, bias, out);
    }
}